// Round 3
// baseline (5046.370 us; speedup 1.0000x reference)
//
#include <hip/hip_runtime.h>

// LightGCN v4: scatter SpMM with dst-swept quarter-buckets.
// R0/R1/R2 evidence: misses are 128B-line-granular, sequence-determined
// (~3.6 TB/s plateau; EMB-split halved demand bytes, FETCH unchanged).
// New structure: p1 bins edges by src-bucket (unchanged); p2 counting-sorts
// each bucket by (src-quarter, dst-bucket) into uint2 {q14|dst, srcrow};
// SpMM = 1172 blocks (293 buckets x 4 quarters of 128 rows), fp32 acc
// [128][65] in LDS (stride 65 -> banks spread by srow%32), edges streamed in
// ascending dst-bucket order so all ~128 co-resident blocks per XCD sweep X
// in phase (each X line fetched ~once per XCD per generation). 1 ds_add
// wave-instr per edge; 4 blocks/CU (33KB LDS) = full occupancy. No padding,
// no prow. Layer 3 = same kernel + sel bitmap (flag rides bit0 of the
// broadcast offset word), writes only sel rows into B for gather_add.
// Workspace 105.5 MB (proven-safe bound ~105.7; >115.2 corrupted in R2).

constexpr int N_USERS = 100000;
constexpr int N_ITEMS = 50000;
constexpr int N_NODES = N_USERS + N_ITEMS;
constexpr int EMB = 64;
constexpr int NNZ = 6400000;
constexpr int BATCH = 4096;

constexpr int BSHIFT = 9;
constexpr int BWIDTH = 1 << BSHIFT;                       // 512 nodes / bucket
constexpr int NB = (N_NODES + BWIDTH - 1) >> BSHIFT;      // 293 buckets
constexpr int NBPAD = 512;
constexpr int BSTRIDE = 22500;   // staging capacity/bucket (mean 21845, +4.4 sigma,
                                 // P(any drop) ~1e-3; p1 guard drops cleanly)

constexpr int TILE = 5120;                                // edges per p1 block
constexpr int P1_BLOCKS = NNZ / TILE;                     // 1250 (exact)
constexpr int EPT1 = TILE / 256;                          // 20

constexpr float QSCALE = 327680.0f;                       // 16384 / 0.05
constexpr float QINV   = 1.0f / 327680.0f;

constexpr int SELW = 4704;                                // sel bitmap words (150000 bits)

struct h4 { _Float16 x, y, z, w; };
typedef _Float16 half8v __attribute__((ext_vector_type(8)));

// ---- init per-bucket staging cursors: gcur[b] = b * BSTRIDE ----
__global__ void gcur_init_kernel(int* __restrict__ gcur) {
    int i = blockIdx.x * blockDim.x + threadIdx.x;
    if (i < NB) gcur[i] = i * BSTRIDE;
}

// ---- pass 1: bin edges into coarse src-buckets, LDS-reordered coalesced flush ----
__global__ void p1_bin_kernel(const int* __restrict__ src, const int* __restrict__ dst,
                              const float* __restrict__ val, int* __restrict__ gcur,
                              uint2* __restrict__ staging) {
    __shared__ int hist[NBPAD];
    __shared__ int gbase[NBPAD];
    __shared__ int cur[NBPAD];
    __shared__ int sbuf[NBPAD];
    __shared__ int lbase[NBPAD];
    __shared__ uint2 ebuf[TILE];                 // 40 KB bucket-sorted tile
    int t = threadIdx.x;
    int tile = blockIdx.x * TILE;
    int srcs[EPT1];
    #pragma unroll
    for (int k = 0; k < EPT1; ++k) srcs[k] = src[tile + t + k * 256];
    for (int i = t; i < NBPAD; i += 256) { hist[i] = 0; cur[i] = 0; }
    __syncthreads();
    #pragma unroll
    for (int k = 0; k < EPT1; ++k) atomicAdd(&hist[srcs[k] >> BSHIFT], 1);
    __syncthreads();
    for (int i = t; i < NB; i += 256) {
        int h = hist[i];
        gbase[i] = (h > 0) ? atomicAdd(&gcur[i], h) : 0;
    }
    for (int i = t; i < NBPAD; i += 256) sbuf[i] = hist[i];
    __syncthreads();
    int* pin = sbuf; int* pout = lbase;
    for (int off = 1; off < NBPAD; off <<= 1) {
        for (int i = t; i < NBPAD; i += 256) {
            int v = pin[i];
            if (i >= off) v += pin[i - off];
            pout[i] = v;
        }
        __syncthreads();
        int* tmp = pin; pin = pout; pout = tmp;
    }
    for (int i = t; i < NBPAD; i += 256) lbase[i] = pin[i] - hist[i];  // exclusive
    __syncthreads();
    #pragma unroll
    for (int k = 0; k < EPT1; ++k) {
        int i = tile + t + k * 256;
        int s = srcs[k];
        int b = s >> BSHIFT;
        int c = atomicAdd(&cur[b], 1);
        int d = dst[i];
        float v = val[i];
        unsigned q = (unsigned)(v * QSCALE);
        if (q > 16383u) q = 16383u;
        ebuf[lbase[b] + c] = make_uint2((q << 18) | (unsigned)d, (unsigned)s);
    }
    __syncthreads();
    #pragma unroll
    for (int k = 0; k < EPT1; ++k) {
        int j = t + k * 256;
        uint2 e = ebuf[j];
        int b = (int)(e.y >> BSHIFT);
        unsigned pos = (unsigned)(gbase[b] + (j - lbase[b]));
        if (pos < (unsigned)((b + 1) * BSTRIDE))   // overflow guard
            staging[pos] = e;
    }
}

// ---- pass 2: per-bucket counting sort by (src-quarter, dst-bucket) ----
// out2[j] = {q14|dst, srcrow(0..511)}; hq[b*4+q] = inclusive edge count of
// quarters <= q within bucket b.
__global__ void p2_sortd_kernel(const int* __restrict__ gcur, const uint2* __restrict__ staging,
                                uint2* __restrict__ out2, int* __restrict__ hq) {
    __shared__ int hist[2048], sA[2048], sB[2048], cur[2048];
    int b = blockIdx.x;
    int t = threadIdx.x;   // 512 threads
    int cnt = gcur[b] - b * BSTRIDE;
    if (cnt > BSTRIDE) cnt = BSTRIDE;
    if (cnt < 0) cnt = 0;
    int sbase = b * BSTRIDE;
    for (int i = t; i < 2048; i += 512) hist[i] = 0;
    __syncthreads();
    for (int j = t; j < cnt; j += 512) {
        uint2 e = staging[sbase + j];
        int key = (((int)(e.y >> 7) & 3) << 9) | (int)((e.x & 0x3FFFFu) >> 9);
        atomicAdd(&hist[key], 1);
    }
    __syncthreads();
    for (int i = t; i < 2048; i += 512) sA[i] = hist[i];
    __syncthreads();
    int* pin = sA; int* pout = sB;
    for (int off = 1; off < 2048; off <<= 1) {
        for (int i = t; i < 2048; i += 512) {
            int v = pin[i];
            if (i >= off) v += pin[i - off];
            pout[i] = v;
        }
        __syncthreads();
        int* tmp = pin; pin = pout; pout = tmp;
    }
    for (int i = t; i < 2048; i += 512) cur[i] = sbase + pin[i] - hist[i];
    if (t < 4) hq[b * 4 + t] = pin[t * 512 + 511];
    __syncthreads();
    for (int j = t; j < cnt; j += 512) {
        uint2 e = staging[sbase + j];
        int key = (((int)(e.y >> 7) & 3) << 9) | (int)((e.x & 0x3FFFFu) >> 9);
        int p = atomicAdd(&cur[key], 1);
        out2[p] = make_uint2(e.x, e.y & 511u);
    }
}

// ---- sel bitmap ----
__global__ void selbm_zero_kernel(unsigned* __restrict__ bm) {
    int i = blockIdx.x * blockDim.x + threadIdx.x;
    if (i < SELW) bm[i] = 0u;
}
__global__ void selbm_set_kernel(const int* __restrict__ users, const int* __restrict__ items,
                                 unsigned* __restrict__ bm) {
    int i = blockIdx.x * blockDim.x + threadIdx.x;
    if (i >= 2 * BATCH) return;
    int node = (i < BATCH) ? users[i] : (N_USERS + items[i - BATCH]);
    atomicOr(&bm[node >> 5], 1u << (node & 31));
}

// ---- init: copy embeddings into fp16 X buffer ----
__global__ void init_kernel(const float4* __restrict__ ue, const float4* __restrict__ ie,
                            h4* __restrict__ x) {
    int i = blockIdx.x * blockDim.x + threadIdx.x;
    const int total = N_NODES * (EMB / 4);
    if (i >= total) return;
    const int usplit = N_USERS * (EMB / 4);
    float4 v = (i < usplit) ? ue[i] : ie[i - usplit];
    x[i] = h4{(_Float16)v.x, (_Float16)v.y, (_Float16)v.z, (_Float16)v.w};
}

// ---- layer-0 acc term from ORIGINAL fp32 embeddings (exact) ----
__global__ void gather_init_kernel(const float* __restrict__ ue, const float* __restrict__ ie,
                                   const int* __restrict__ users, const int* __restrict__ items,
                                   float* __restrict__ accb) {
    int gid = blockIdx.x * blockDim.x + threadIdx.x;
    int w = gid >> 6;
    int lane = threadIdx.x & 63;
    if (w >= BATCH * 2) return;
    int b = w >> 1;
    float v;
    if (w & 1) v = ie[(long long)items[b] * EMB + lane];
    else       v = ue[(long long)users[b] * EMB + lane];
    accb[(long long)w * EMB + lane] = v;
}

// ---- accb += x[sel] (fp16 source) ----
__global__ void gather_add_kernel(const _Float16* __restrict__ x, const int* __restrict__ users,
                                  const int* __restrict__ items, float* __restrict__ accb) {
    int gid = blockIdx.x * blockDim.x + threadIdx.x;
    int w = gid >> 6;
    int lane = threadIdx.x & 63;
    if (w >= BATCH * 2) return;
    int b = w >> 1;
    int node = (w & 1) ? (N_USERS + items[b]) : users[b];
    accb[(long long)w * EMB + lane] += (float)x[(unsigned)node * EMB + lane];
}

// ---- scatter SpMM: block = (bucket, quarter) = 128 output rows.
// fp32 acc[128][65] in LDS; 8-lane group per edge (lane = 8 dims); holder
// lane decodes once and broadcasts {voff|selflag, val, lrow} via shfl. ----
template<bool SEL>
__global__ __launch_bounds__(512)
void spmm_scatter_kernel(const int* __restrict__ gcur, const int* __restrict__ hq,
                         const uint2* __restrict__ out2, const unsigned* __restrict__ selbm,
                         const _Float16* __restrict__ x, _Float16* __restrict__ y) {
    __shared__ float acc[128 * 65];                 // 33,280 B
    int bid = blockIdx.x;
    int b = bid >> 2, q = bid & 3;
    int tid = threadIdx.x;
    for (int i = tid; i < 128 * 65; i += 512) acc[i] = 0.f;
    int cntT = gcur[b] - b * BSTRIDE;
    if (cntT > BSTRIDE) cntT = BSTRIDE;
    if (cntT < 0) cntT = 0;
    int hqe = hq[b * 4 + q];
    if (hqe > cntT) hqe = cntT;
    int start = (q > 0) ? hq[b * 4 + q - 1] : 0;
    if (start > hqe) start = hqe;
    int cnt = hqe - start;
    const uint2* ep = out2 + (size_t)b * BSTRIDE + start;
    int l8 = tid & 7;
    int qb = tid & 56;
    unsigned li16 = (unsigned)l8 * 16u;
    const char* xb = (const char*)x;
    __syncthreads();
    int j0 = (tid >> 3) * 8;
    if (j0 < cnt) {
        uint2 e = ep[j0 + l8];
        for (; j0 < cnt; j0 += 512) {
            uint2 en = ep[j0 + 512 + l8];            // prefetch (over-read safe)
            // holder decode (once per edge)
            unsigned d = e.x & 0x3FFFFu;
            if (d >= (unsigned)N_NODES) d = 0u;      // junk-slot guard
            unsigned voff = d << 7;
            float v = ((float)(e.x >> 18) + 0.5f) * QINV;
            int srow = (int)(e.y & 511u);
            int lr = srow & 127;
            if (SEL) {
                int node = (b << 9) + srow;
                voff |= (selbm[node >> 5] >> (node & 31)) & 1u;
            }
            int nrem = cnt - j0;
            #pragma unroll
            for (int t = 0; t < 8; ++t) {
                unsigned o = (unsigned)__shfl((int)voff, qb + t, 64);
                float vv = __shfl(v, qb + t, 64);
                int sr = __shfl(lr, qb + t, 64);
                bool act = (t < nrem);
                if (SEL) act = act && (o & 1u);
                if (act) {
                    half8v hx = *(const half8v*)(xb + ((o & 0xFFFFFF80u) | li16));
                    int ab = (sr << 6) + sr + (l8 << 3);     // sr*65 + l8*8
                    #pragma unroll
                    for (int k = 0; k < 8; ++k)
                        atomicAdd(&acc[ab + k], vv * (float)hx[k]);
                }
            }
            e = en;
        }
    }
    __syncthreads();
    // writeback: 128 rows, group g writes rows g and g+64; lane l8 -> 16B slice
    int g = tid >> 3;
    int node0 = (b << 9) + (q << 7);
    #pragma unroll
    for (int i = 0; i < 2; ++i) {
        int r = g + i * 64;
        int node = node0 + r;
        if (node >= N_NODES) continue;
        if (SEL) {
            unsigned f = (selbm[node >> 5] >> (node & 31)) & 1u;
            if (!f) continue;
        }
        int ab = (r << 6) + r + (l8 << 3);
        half8v hv;
        #pragma unroll
        for (int k = 0; k < 8; ++k) hv[k] = (_Float16)acc[ab + k];
        *(half8v*)((char*)y + (((size_t)node) << 7) + li16) = hv;
    }
}

// ---- scores ----
__global__ void score_kernel(const float* __restrict__ accb, float* __restrict__ out) {
    int gid = blockIdx.x * blockDim.x + threadIdx.x;
    int b = gid >> 6;
    int lane = threadIdx.x & 63;
    if (b >= BATCH) return;
    float a = accb[(long long)(2 * b) * EMB + lane];
    float c = accb[(long long)(2 * b + 1) * EMB + lane];
    float p = a * c;
    #pragma unroll
    for (int off = 32; off > 0; off >>= 1) p += __shfl_down(p, off, 64);
    if (lane == 0) out[b] = p * (1.0f / 16.0f);
}

extern "C" void kernel_launch(void* const* d_in, const int* in_sizes, int n_in,
                              void* d_out, int out_size, void* d_ws, size_t ws_size,
                              hipStream_t stream) {
    const float* user_emb  = (const float*)d_in[0];
    const float* item_emb  = (const float*)d_in[1];
    const float* graph_val = (const float*)d_in[2];
    const int*   graph_src = (const int*)d_in[3];
    const int*   graph_dst = (const int*)d_in[4];
    const int*   users     = (const int*)d_in[5];
    const int*   items     = (const int*)d_in[6];
    float* out = (float*)d_out;

    // workspace layout — 105.5 MB total.
    // region0 (52.74 MB): staging during CSR build; afterwards A|B|accb.
    // region1 (52.74 MB): out2 (dst-sorted uint2 edge stream).
    char* base = (char*)d_ws;
    const size_t STAGE_BYTES = (size_t)BSTRIDE * NB * 8;        // 52,740,000
    const size_t XBYTES = (size_t)N_NODES * EMB * 2;            // 19,200,000
    uint2*    staging = (uint2*)base;
    _Float16* A       = (_Float16*)base;
    _Float16* B       = (_Float16*)(base + XBYTES);
    float*    accb    = (float*)(base + 2 * XBYTES);            // 2.1 MB, ends 40.5 MB
    uint2*    out2    = (uint2*)(base + STAGE_BYTES);
    int*      gcur    = (int*)(base + 2 * STAGE_BYTES);         // 512 ints
    int*      hq      = gcur + 512;                             // 1172 ints (pad 1216)
    unsigned* selbm   = (unsigned*)(hq + 1216);                 // 4704 words

    const int totalv4 = N_NODES * (EMB / 4);
    const int vblocks = (totalv4 + 255) / 256;
    const int wblocks = (BATCH * 2 * 64) / 256;                 // 2048
    const int scblocks = NB * 4;                                // 1172

    // ---- CSR build: src-bucket staging, then (quarter, dst-bucket) sort ----
    gcur_init_kernel<<<(NB + 255) / 256, 256, 0, stream>>>(gcur);
    p1_bin_kernel<<<P1_BLOCKS, 256, 0, stream>>>(graph_src, graph_dst, graph_val,
                                                 gcur, staging);
    p2_sortd_kernel<<<NB, 512, 0, stream>>>(gcur, staging, out2, hq);
    selbm_zero_kernel<<<(SELW + 255) / 256, 256, 0, stream>>>(selbm);
    selbm_set_kernel<<<(2 * BATCH + 255) / 256, 256, 0, stream>>>(users, items, selbm);

    // ---- embeddings (staging now dead; A/B/accb overlay it) ----
    init_kernel<<<vblocks, 256, 0, stream>>>((const float4*)user_emb,
                                             (const float4*)item_emb, (h4*)A);
    gather_init_kernel<<<wblocks, 256, 0, stream>>>(user_emb, item_emb, users, items, accb);

    // layer 1: B = G.A ; accb += B[sel]
    spmm_scatter_kernel<false><<<scblocks, 512, 0, stream>>>(gcur, hq, out2, selbm, A, B);
    gather_add_kernel<<<wblocks, 256, 0, stream>>>(B, users, items, accb);

    // layer 2: A = G.B ; accb += A[sel]
    spmm_scatter_kernel<false><<<scblocks, 512, 0, stream>>>(gcur, hq, out2, selbm, B, A);
    gather_add_kernel<<<wblocks, 256, 0, stream>>>(A, users, items, accb);

    // layer 3: sel rows only -> B; accb += B[sel]
    spmm_scatter_kernel<true><<<scblocks, 512, 0, stream>>>(gcur, hq, out2, selbm, A, B);
    gather_add_kernel<<<wblocks, 256, 0, stream>>>(B, users, items, accb);

    score_kernel<<<(BATCH * 64) / 256, 256, 0, stream>>>(accb, out);
}

// Round 4
// 760.560 us; speedup vs baseline: 6.6351x; 6.6351x over previous
//
#include <hip/hip_runtime.h>

// LightGCN v5: dst-ordered gather SpMM.
// Evidence R0-R3: gather SpMM pinned at ~3.65 TB/s L2-miss traffic, miss
// volume determined by the line-access SEQUENCE (R2: halving demand bytes
// left FETCH unchanged); LDS-atomic scatter (R3) serializes on the LDS
// atomic pipe (51M ds_atomic instrs -> 22x slowdown). This round: keep R1's
// 8-lane-group gather SpMM verbatim, but insert p1.5 = per-bucket counting
// sort by fine dst (dst>>7, 2048 bins) so every row's edge walk ascends
// dst-space. All concurrently-resident rows sweep X in phase -> instantaneous
// working set per XCD-L2 is a moving front of a few MB instead of 19.2 MB.
// p2's atomic-cursor redistribution preserves dst order within each row to
// ~+-512-element scheduling jitter (~1-2 MB dst-space) - good enough.
// Memory: staging (52.7MB) -> epack+prow (31.8MB) overlay after p1.5;
// out2 (52.7MB) -> A|B|accb (40.5MB) overlay after p2. Total 105.5 MB
// (proven-safe ~105.7; >115.2 corrupted harness inputs in R2 of session 1).
// Pad slots are zero words: dst=0, q=0 -> val ~1.5e-6, contributes <=1e-5/row.

constexpr int N_USERS = 100000;
constexpr int N_ITEMS = 50000;
constexpr int N_NODES = N_USERS + N_ITEMS;
constexpr int EMB = 64;
constexpr int NNZ = 6400000;
constexpr int BATCH = 4096;

constexpr int BSHIFT = 9;
constexpr int BWIDTH = 1 << BSHIFT;                       // 512 nodes / bucket
constexpr int NB = (N_NODES + BWIDTH - 1) >> BSHIFT;      // 293 buckets
constexpr int NBPAD = 512;
constexpr int BSTRIDE = 22500;   // staging capacity/bucket (mean 21845, +4.4 sigma;
                                 // overflow p~1e-3, guard drops cleanly - as R3)
constexpr int PBSTRIDE = 26624;  // padded epack slots/bucket: 512*52 (+17 sigma)

constexpr int TILE = 5120;                                // edges per p1 block
constexpr int P1_BLOCKS = NNZ / TILE;                     // 1250 (exact)
constexpr int EPT1 = TILE / 256;                          // 20

constexpr float QSCALE = 327680.0f;                       // 16384 / 0.05
constexpr float QINV   = 1.0f / 327680.0f;

struct h4 { _Float16 x, y, z, w; };
typedef _Float16 half8v __attribute__((ext_vector_type(8)));

// ---- init per-bucket staging cursors: gcur[b] = b * BSTRIDE ----
__global__ void gcur_init_kernel(int* __restrict__ gcur) {
    int i = blockIdx.x * blockDim.x + threadIdx.x;
    if (i < NB) gcur[i] = i * BSTRIDE;
}

// ---- pass 1: bin edges into coarse src-buckets, LDS-reordered coalesced flush ----
__global__ void p1_bin_kernel(const int* __restrict__ src, const int* __restrict__ dst,
                              const float* __restrict__ val, int* __restrict__ gcur,
                              uint2* __restrict__ staging) {
    __shared__ int hist[NBPAD];
    __shared__ int gbase[NBPAD];
    __shared__ int cur[NBPAD];
    __shared__ int sbuf[NBPAD];
    __shared__ int lbase[NBPAD];
    __shared__ uint2 ebuf[TILE];                 // 40 KB bucket-sorted tile
    int t = threadIdx.x;
    int tile = blockIdx.x * TILE;
    int srcs[EPT1];
    #pragma unroll
    for (int k = 0; k < EPT1; ++k) srcs[k] = src[tile + t + k * 256];
    for (int i = t; i < NBPAD; i += 256) { hist[i] = 0; cur[i] = 0; }
    __syncthreads();
    #pragma unroll
    for (int k = 0; k < EPT1; ++k) atomicAdd(&hist[srcs[k] >> BSHIFT], 1);
    __syncthreads();
    for (int i = t; i < NB; i += 256) {
        int h = hist[i];
        gbase[i] = (h > 0) ? atomicAdd(&gcur[i], h) : 0;
    }
    for (int i = t; i < NBPAD; i += 256) sbuf[i] = hist[i];
    __syncthreads();
    int* pin = sbuf; int* pout = lbase;
    for (int off = 1; off < NBPAD; off <<= 1) {
        for (int i = t; i < NBPAD; i += 256) {
            int v = pin[i];
            if (i >= off) v += pin[i - off];
            pout[i] = v;
        }
        __syncthreads();
        int* tmp = pin; pin = pout; pout = tmp;
    }
    for (int i = t; i < NBPAD; i += 256) lbase[i] = pin[i] - hist[i];  // exclusive
    __syncthreads();
    #pragma unroll
    for (int k = 0; k < EPT1; ++k) {
        int i = tile + t + k * 256;
        int s = srcs[k];
        int b = s >> BSHIFT;
        int c = atomicAdd(&cur[b], 1);
        int d = dst[i];
        float v = val[i];
        unsigned q = (unsigned)(v * QSCALE);
        if (q > 16383u) q = 16383u;
        ebuf[lbase[b] + c] = make_uint2((q << 18) | (unsigned)d, (unsigned)s);
    }
    __syncthreads();
    #pragma unroll
    for (int k = 0; k < EPT1; ++k) {
        int j = t + k * 256;
        uint2 e = ebuf[j];
        int b = (int)(e.y >> BSHIFT);
        unsigned pos = (unsigned)(gbase[b] + (j - lbase[b]));
        if (pos < (unsigned)((b + 1) * BSTRIDE))   // overflow guard
            staging[pos] = e;
    }
}

// ---- pass 1.5: per-bucket counting sort by FINE DST (dst>>7, 2048 bins).
// Output out2 = same bucket layout, edges in ascending-dst order. ----
__global__ void p1p5_dsort_kernel(const int* __restrict__ gcur,
                                  const uint2* __restrict__ staging,
                                  uint2* __restrict__ out2) {
    __shared__ int hist[2048], sA[2048], sB[2048], cur[2048];
    int b = blockIdx.x;
    int t = threadIdx.x;   // 512 threads
    int cnt = gcur[b] - b * BSTRIDE;
    if (cnt > BSTRIDE) cnt = BSTRIDE;
    if (cnt < 0) cnt = 0;
    int sbase = b * BSTRIDE;
    for (int i = t; i < 2048; i += 512) hist[i] = 0;
    __syncthreads();
    for (int j = t; j < cnt; j += 512) {
        uint2 e = staging[sbase + j];
        int key = (int)((e.x & 0x3FFFFu) >> 7);          // 0..1171
        atomicAdd(&hist[key], 1);
    }
    __syncthreads();
    for (int i = t; i < 2048; i += 512) sA[i] = hist[i];
    __syncthreads();
    int* pin = sA; int* pout = sB;
    for (int off = 1; off < 2048; off <<= 1) {
        for (int i = t; i < 2048; i += 512) {
            int v = pin[i];
            if (i >= off) v += pin[i - off];
            pout[i] = v;
        }
        __syncthreads();
        int* tmp = pin; pin = pout; pout = tmp;
    }
    for (int i = t; i < 2048; i += 512) cur[i] = sbase + pin[i] - hist[i];
    __syncthreads();
    for (int j = t; j < cnt; j += 512) {
        uint2 e = staging[sbase + j];
        int key = (int)((e.x & 0x3FFFFu) >> 7);
        int p = atomicAdd(&cur[key], 1);
        out2[p] = e;
    }
}

// ---- pass 2: per-bucket counting sort by src row into PADDED epack + prow.
// Reads dst-sorted out2 sequentially -> per-row edge order stays ~ascending
// in dst (+- scheduling jitter). Pad slots zeroed here (no global memset);
// each row starts 8-aligned, length 8*ceil(c/8). 512 threads = BWIDTH. ----
__global__ void p2_sort_kernel(const int* __restrict__ gcur, const uint2* __restrict__ out2,
                               unsigned* __restrict__ epack, unsigned* __restrict__ prow) {
    __shared__ int hist[BWIDTH], sA[BWIDTH], sB[BWIDTH], cur[BWIDTH];
    int b = blockIdx.x;
    int t = threadIdx.x;   // 512 threads
    int cnt = gcur[b] - b * BSTRIDE;
    if (cnt > BSTRIDE) cnt = BSTRIDE;
    if (cnt < 0) cnt = 0;
    int sbase = b * BSTRIDE;
    hist[t] = 0;
    __syncthreads();
    for (int j = t; j < cnt; j += 512) {
        uint2 e = out2[sbase + j];
        atomicAdd(&hist[e.y & (BWIDTH - 1)], 1);
    }
    __syncthreads();
    // scan of window counts pw_i = ceil(c_i/8)
    sA[t] = (hist[t] + 7) >> 3;
    __syncthreads();
    int* pin = sA; int* pout = sB;
    for (int off = 1; off < BWIDTH; off <<= 1) {
        int v = pin[t];
        if (t >= off) v += pin[t - off];
        pout[t] = v;
        __syncthreads();
        int* tmp = pin; pin = pout; pout = tmp;
    }
    {
        int c = hist[t];
        int pw = (c + 7) >> 3;
        int ps = pin[t] - pw;                       // exclusive window prefix
        unsigned poff = (unsigned)(b * PBSTRIDE + 8 * ps);
        // overflow guards: clamp windows to bucket region (p ~ 1e-12) and to
        // the 4-bit nwin field (rows >120 edges; P(Poisson(42.7)>120) ~ 0)
        int fit = (PBSTRIDE - 8 * ps) >> 3;
        if (fit < 0) fit = 0;
        if (pw > fit) pw = fit;
        if (pw > 15) pw = 15;
        cur[t] = (int)poff;
        int node = (b << BSHIFT) + t;
        if (node < N_NODES) prow[node] = (poff << 4) | (unsigned)pw;
        // zero this row's pad slots (replaces the global memset)
        for (int s = c; s < 8 * pw; ++s) epack[poff + s] = 0;
    }
    __syncthreads();
    unsigned bend = (unsigned)((b + 1) * PBSTRIDE);
    for (int j = t; j < cnt; j += 512) {
        uint2 e = out2[sbase + j];
        int p = atomicAdd(&cur[e.y & (BWIDTH - 1)], 1);
        if ((unsigned)p < bend) epack[p] = e.x;
    }
}

// ---- init: copy embeddings into fp16 X buffer ----
__global__ void init_kernel(const float4* __restrict__ ue, const float4* __restrict__ ie,
                            h4* __restrict__ x) {
    int i = blockIdx.x * blockDim.x + threadIdx.x;
    const int total = N_NODES * (EMB / 4);
    if (i >= total) return;
    const int usplit = N_USERS * (EMB / 4);
    float4 v = (i < usplit) ? ue[i] : ie[i - usplit];
    x[i] = h4{(_Float16)v.x, (_Float16)v.y, (_Float16)v.z, (_Float16)v.w};
}

// ---- layer-0 acc term from ORIGINAL fp32 embeddings (exact) ----
__global__ void gather_init_kernel(const float* __restrict__ ue, const float* __restrict__ ie,
                                   const int* __restrict__ users, const int* __restrict__ items,
                                   float* __restrict__ accb) {
    int gid = blockIdx.x * blockDim.x + threadIdx.x;
    int w = gid >> 6;
    int lane = threadIdx.x & 63;
    if (w >= BATCH * 2) return;
    int b = w >> 1;
    float v;
    if (w & 1) v = ie[(long long)items[b] * EMB + lane];
    else       v = ue[(long long)users[b] * EMB + lane];
    accb[(long long)w * EMB + lane] = v;
}

// ---- accb += x[sel] (fp16 source) ----
__global__ void gather_add_kernel(const _Float16* __restrict__ x, const int* __restrict__ users,
                                  const int* __restrict__ items, float* __restrict__ accb) {
    int gid = blockIdx.x * blockDim.x + threadIdx.x;
    int w = gid >> 6;
    int lane = threadIdx.x & 63;
    if (w >= BATCH * 2) return;
    int b = w >> 1;
    int node = (w & 1) ? (N_USERS + items[b]) : users[b];
    accb[(long long)w * EMB + lane] += (float)x[(unsigned)node * EMB + lane];
}

// ---- padded row gather: 8-lane group per row, static 8-edge windows.
//      Holder lane decodes (byte-offset, val) once, broadcasts via shfl;
//      each lane owns 8 dims -> no cross-lane reduction. ----
__device__ __forceinline__ void row_gather_p8(unsigned pr, int lane,
                                              const unsigned* __restrict__ epack,
                                              const _Float16* __restrict__ x,
                                              float acc[8]) {
    const int l8 = lane & 7;
    const int qb = lane & 56;                        // group base lane in wave
    const unsigned li8b = (unsigned)l8 * 16u;        // byte offset within 128B row
    float a0 = 0, a1 = 0, a2 = 0, a3 = 0, a4 = 0, a5 = 0, a6 = 0, a7 = 0;
    float b0 = 0, b1 = 0, b2 = 0, b3 = 0, b4 = 0, b5 = 0, b6 = 0, b7 = 0;
    const unsigned* ep = epack + (pr >> 4);
    const char* xb = (const char*)x;
    int nwin = (int)(pr & 15u);
    if (nwin > 0) {
        unsigned e = ep[l8];
        for (int w = 0; w < nwin; ++w) {
            unsigned en = ep[8 + l8];                // prefetch next window
            ep += 8;                                 // (over-read lands in prow, safe)
            unsigned voff = (e & 0x3FFFFu) << 7;     // row byte offset
            float v = ((float)(e >> 18) + 0.5f) * QINV;
            #pragma unroll
            for (int t = 0; t < 8; t += 2) {
                unsigned offA = (unsigned)__shfl((int)voff, qb + t, 64);
                unsigned offB = (unsigned)__shfl((int)voff, qb + t + 1, 64);
                float vA = __shfl(v, qb + t, 64);
                float vB = __shfl(v, qb + t + 1, 64);
                const half8v hA = *(const half8v*)(xb + (offA | li8b));
                const half8v hB = *(const half8v*)(xb + (offB | li8b));
                a0 += vA * (float)hA[0];  a1 += vA * (float)hA[1];
                a2 += vA * (float)hA[2];  a3 += vA * (float)hA[3];
                a4 += vA * (float)hA[4];  a5 += vA * (float)hA[5];
                a6 += vA * (float)hA[6];  a7 += vA * (float)hA[7];
                b0 += vB * (float)hB[0];  b1 += vB * (float)hB[1];
                b2 += vB * (float)hB[2];  b3 += vB * (float)hB[3];
                b4 += vB * (float)hB[4];  b5 += vB * (float)hB[5];
                b6 += vB * (float)hB[6];  b7 += vB * (float)hB[7];
            }
            e = en;
        }
    }
    acc[0] = a0 + b0; acc[1] = a1 + b1; acc[2] = a2 + b2; acc[3] = a3 + b3;
    acc[4] = a4 + b4; acc[5] = a5 + b5; acc[6] = a6 + b6; acc[7] = a7 + b7;
}

// ---- full SpMM: one 8-lane group per output row, fp16 in/out ----
__global__ void spmm_full_kernel(const unsigned* __restrict__ prow,
                                 const unsigned* __restrict__ epack,
                                 const _Float16* __restrict__ x, _Float16* __restrict__ y) {
    int gid = blockIdx.x * blockDim.x + threadIdx.x;
    int row = gid >> 3;
    if (row >= N_NODES) return;
    int lane = threadIdx.x & 63;
    float acc[8];
    row_gather_p8(prow[row], lane, epack, x, acc);
    half8v h;
    #pragma unroll
    for (int i = 0; i < 8; ++i) h[i] = (_Float16)acc[i];
    *(half8v*)(y + ((unsigned)row << 6) + (unsigned)(lane & 7) * 8) = h;
}

// ---- layer-3 SpMM for selected rows only; adds straight into accb ----
__global__ void spmm_sel_kernel(const unsigned* __restrict__ prow,
                                const unsigned* __restrict__ epack,
                                const _Float16* __restrict__ x, const int* __restrict__ users,
                                const int* __restrict__ items, float* __restrict__ accb) {
    int gid = blockIdx.x * blockDim.x + threadIdx.x;
    int g = gid >> 3;
    if (g >= BATCH * 2) return;
    int lane = threadIdx.x & 63;
    int b = g >> 1;
    int node = (g & 1) ? (N_USERS + items[b]) : users[b];
    float acc[8];
    row_gather_p8(prow[node], lane, epack, x, acc);
    float4* p = (float4*)(accb + ((long long)g << 6) + (lane & 7) * 8);
    float4 c0 = p[0], c1 = p[1];
    c0.x += acc[0]; c0.y += acc[1]; c0.z += acc[2]; c0.w += acc[3];
    c1.x += acc[4]; c1.y += acc[5]; c1.z += acc[6]; c1.w += acc[7];
    p[0] = c0; p[1] = c1;
}

// ---- scores ----
__global__ void score_kernel(const float* __restrict__ accb, float* __restrict__ out) {
    int gid = blockIdx.x * blockDim.x + threadIdx.x;
    int b = gid >> 6;
    int lane = threadIdx.x & 63;
    if (b >= BATCH) return;
    float a = accb[(long long)(2 * b) * EMB + lane];
    float c = accb[(long long)(2 * b + 1) * EMB + lane];
    float p = a * c;
    #pragma unroll
    for (int off = 32; off > 0; off >>= 1) p += __shfl_down(p, off, 64);
    if (lane == 0) out[b] = p * (1.0f / 16.0f);
}

extern "C" void kernel_launch(void* const* d_in, const int* in_sizes, int n_in,
                              void* d_out, int out_size, void* d_ws, size_t ws_size,
                              hipStream_t stream) {
    const float* user_emb  = (const float*)d_in[0];
    const float* item_emb  = (const float*)d_in[1];
    const float* graph_val = (const float*)d_in[2];
    const int*   graph_src = (const int*)d_in[3];
    const int*   graph_dst = (const int*)d_in[4];
    const int*   users     = (const int*)d_in[5];
    const int*   items     = (const int*)d_in[6];
    float* out = (float*)d_out;

    // workspace layout — 105.5 MB total.
    // region0 (52.74 MB): staging (p1..p1.5) -> epack+prow (31.8 MB, p2 on).
    // region1 (52.74 MB): out2 (p1.5..p2)    -> A|B|accb (40.5 MB, init on).
    char* base = (char*)d_ws;
    const size_t STAGE_BYTES = (size_t)BSTRIDE * NB * 8;        // 52,740,000
    const size_t XBYTES = (size_t)N_NODES * EMB * 2;            // 19,200,000
    const size_t PB_SLOTS = (size_t)PBSTRIDE * NB;              // 7,800,832
    uint2*    staging = (uint2*)base;
    unsigned* epack   = (unsigned*)base;                        // overlays staging
    unsigned* prow    = epack + PB_SLOTS;                       // 0.6 MB, ends 31.8 MB
    uint2*    out2    = (uint2*)(base + STAGE_BYTES);
    _Float16* A       = (_Float16*)(base + STAGE_BYTES);        // overlays out2
    _Float16* B       = (_Float16*)(base + STAGE_BYTES + XBYTES);
    float*    accb    = (float*)(base + STAGE_BYTES + 2 * XBYTES); // 2.1 MB, ends 40.5
    int*      gcur    = (int*)(base + 2 * STAGE_BYTES);         // 512 ints

    const int totalv4 = N_NODES * (EMB / 4);
    const int vblocks = (totalv4 + 255) / 256;
    const int wblocks = (BATCH * 2 * 64) / 256;                 // 2048
    const int sblocks = (N_NODES * 8 + 255) / 256;              // 4688 (32 rows/block)
    const int selblocks = (BATCH * 2 * 8) / 256;                // 256

    // ---- CSR build: src-bucket staging, dst fine-sort, row sort ----
    gcur_init_kernel<<<(NB + 255) / 256, 256, 0, stream>>>(gcur);
    p1_bin_kernel<<<P1_BLOCKS, 256, 0, stream>>>(graph_src, graph_dst, graph_val,
                                                 gcur, staging);
    p1p5_dsort_kernel<<<NB, 512, 0, stream>>>(gcur, staging, out2);
    p2_sort_kernel<<<NB, 512, 0, stream>>>(gcur, out2, epack, prow);

    // ---- embeddings (out2 now dead; A/B/accb overlay it) ----
    init_kernel<<<vblocks, 256, 0, stream>>>((const float4*)user_emb,
                                             (const float4*)item_emb, (h4*)A);
    gather_init_kernel<<<wblocks, 256, 0, stream>>>(user_emb, item_emb, users, items, accb);

    // layer 1: B = G.A ; accb += B[sel]
    spmm_full_kernel<<<sblocks, 256, 0, stream>>>(prow, epack, A, B);
    gather_add_kernel<<<wblocks, 256, 0, stream>>>(B, users, items, accb);

    // layer 2: A = G.B ; accb += A[sel]
    spmm_full_kernel<<<sblocks, 256, 0, stream>>>(prow, epack, B, A);
    gather_add_kernel<<<wblocks, 256, 0, stream>>>(A, users, items, accb);

    // layer 3: selected rows only
    spmm_sel_kernel<<<selblocks, 256, 0, stream>>>(prow, epack, A, users, items, accb);

    score_kernel<<<(BATCH * 64) / 256, 256, 0, stream>>>(accb, out);
}

// Round 5
// 489.311 us; speedup vs baseline: 10.3132x; 1.5544x over previous
//
#include <hip/hip_runtime.h>

// LightGCN v6: int8-quantized gather SpMM.
// Evidence R0-R4: spmm pinned at ~3.67 TB/s L2-miss fetch; miss volume is
// 128B-line-granular (R2: half-row reads left per-pass FETCH unchanged) and
// RANDOM edge order beats loosely-sorted (R4: dst-sort doubled FETCH via
// phase drift). So: shrink the lines themselves. X rows stored as 64 u8
// (biased +128) + per-row fp32 scale (600 KB, L2-hot): working set 19.2->9.6
// MB, one 128B line = TWO node rows (~85 uses/line), demand bytes halved.
// Inner loop: acc_d = sum(vs*byte_d) - 128*sum(vs)  (bias folded into one
// running scalar S). Quantization fused into spmm epilogue (group max via
// 3 shfl_xor). Layer-0 acc term exact fp32; final layer adds fp32 into accb
// (no output quant). Build passes = R1/R2 proven versions (window-8 padded
// epack, memset-free p2 @512 threads). Workspace ~87 MB (safe bound ~105.7).

constexpr int N_USERS = 100000;
constexpr int N_ITEMS = 50000;
constexpr int N_NODES = N_USERS + N_ITEMS;
constexpr int EMB = 64;
constexpr int NNZ = 6400000;
constexpr int BATCH = 4096;

constexpr int BSHIFT = 9;
constexpr int BWIDTH = 1 << BSHIFT;                       // 512 nodes / bucket
constexpr int NB = (N_NODES + BWIDTH - 1) >> BSHIFT;      // 293 buckets
constexpr int NBPAD = 512;
constexpr int BSTRIDE = 23500;   // staging capacity/bucket (mean 21845, +11 sigma)
constexpr int PBSTRIDE = 26624;  // padded epack slots/bucket: 512*52 (+17 sigma)

constexpr int TILE = 5120;                                // edges per p1 block
constexpr int P1_BLOCKS = NNZ / TILE;                     // 1250 (exact)
constexpr int EPT1 = TILE / 256;                          // 20

constexpr float QSCALE = 327680.0f;                       // 16384 / 0.05
constexpr float QINV   = 1.0f / 327680.0f;

// ---- init per-bucket staging cursors: gcur[b] = b * BSTRIDE ----
__global__ void gcur_init_kernel(int* __restrict__ gcur) {
    int i = blockIdx.x * blockDim.x + threadIdx.x;
    if (i < NB) gcur[i] = i * BSTRIDE;
}

// ---- pass 1: bin edges into coarse src-buckets, LDS-reordered coalesced flush ----
__global__ void p1_bin_kernel(const int* __restrict__ src, const int* __restrict__ dst,
                              const float* __restrict__ val, int* __restrict__ gcur,
                              uint2* __restrict__ staging) {
    __shared__ int hist[NBPAD];
    __shared__ int gbase[NBPAD];
    __shared__ int cur[NBPAD];
    __shared__ int sbuf[NBPAD];
    __shared__ int lbase[NBPAD];
    __shared__ uint2 ebuf[TILE];                 // 40 KB bucket-sorted tile
    int t = threadIdx.x;
    int tile = blockIdx.x * TILE;
    int srcs[EPT1];
    #pragma unroll
    for (int k = 0; k < EPT1; ++k) srcs[k] = src[tile + t + k * 256];
    for (int i = t; i < NBPAD; i += 256) { hist[i] = 0; cur[i] = 0; }
    __syncthreads();
    #pragma unroll
    for (int k = 0; k < EPT1; ++k) atomicAdd(&hist[srcs[k] >> BSHIFT], 1);
    __syncthreads();
    for (int i = t; i < NB; i += 256) {
        int h = hist[i];
        gbase[i] = (h > 0) ? atomicAdd(&gcur[i], h) : 0;
    }
    for (int i = t; i < NBPAD; i += 256) sbuf[i] = hist[i];
    __syncthreads();
    int* pin = sbuf; int* pout = lbase;
    for (int off = 1; off < NBPAD; off <<= 1) {
        for (int i = t; i < NBPAD; i += 256) {
            int v = pin[i];
            if (i >= off) v += pin[i - off];
            pout[i] = v;
        }
        __syncthreads();
        int* tmp = pin; pin = pout; pout = tmp;
    }
    for (int i = t; i < NBPAD; i += 256) lbase[i] = pin[i] - hist[i];  // exclusive
    __syncthreads();
    #pragma unroll
    for (int k = 0; k < EPT1; ++k) {
        int i = tile + t + k * 256;
        int s = srcs[k];
        int b = s >> BSHIFT;
        int c = atomicAdd(&cur[b], 1);
        int d = dst[i];
        float v = val[i];
        unsigned q = (unsigned)(v * QSCALE);
        if (q > 16383u) q = 16383u;
        ebuf[lbase[b] + c] = make_uint2((q << 18) | (unsigned)d, (unsigned)s);
    }
    __syncthreads();
    #pragma unroll
    for (int k = 0; k < EPT1; ++k) {
        int j = t + k * 256;
        uint2 e = ebuf[j];
        int b = (int)(e.y >> BSHIFT);
        unsigned pos = (unsigned)(gbase[b] + (j - lbase[b]));
        if (pos < (unsigned)((b + 1) * BSTRIDE))   // overflow guard (p ~ 1e-10)
            staging[pos] = e;
    }
}

// ---- pass 2: per-bucket counting sort into PADDED epack + prow descriptors ----
// 512 threads (one per bucket row). Pad slots of each row zeroed here (no
// global memset); each row starts 8-aligned, length 8*ceil(c/8). ----
__global__ void p2_sort_kernel(const int* __restrict__ gcur, const uint2* __restrict__ staging,
                               unsigned* __restrict__ epack, unsigned* __restrict__ prow) {
    __shared__ int hist[BWIDTH], sA[BWIDTH], sB[BWIDTH], cur[BWIDTH];
    int b = blockIdx.x;
    int t = threadIdx.x;   // 512 threads
    int cnt = gcur[b] - b * BSTRIDE;
    if (cnt > BSTRIDE) cnt = BSTRIDE;
    int sbase = b * BSTRIDE;
    hist[t] = 0;
    __syncthreads();
    for (int j = t; j < cnt; j += 512) {
        uint2 e = staging[sbase + j];
        atomicAdd(&hist[e.y & (BWIDTH - 1)], 1);
    }
    __syncthreads();
    // scan of window counts pw_i = ceil(c_i/8)
    sA[t] = (hist[t] + 7) >> 3;
    __syncthreads();
    int* pin = sA; int* pout = sB;
    for (int off = 1; off < BWIDTH; off <<= 1) {
        int v = pin[t];
        if (t >= off) v += pin[t - off];
        pout[t] = v;
        __syncthreads();
        int* tmp = pin; pin = pout; pout = tmp;
    }
    {
        int c = hist[t];
        int pw = (c + 7) >> 3;
        int ps = pin[t] - pw;                       // exclusive window prefix
        unsigned poff = (unsigned)(b * PBSTRIDE + 8 * ps);
        // overflow guards: clamp windows to bucket region (p ~ 1e-12) and to
        // the 4-bit nwin field (rows >120 edges; P(Poisson(42.7)>120) ~ 0)
        int fit = (PBSTRIDE - 8 * ps) >> 3;
        if (fit < 0) fit = 0;
        if (pw > fit) pw = fit;
        if (pw > 15) pw = 15;
        cur[t] = (int)poff;
        int node = (b << BSHIFT) + t;
        if (node < N_NODES) prow[node] = (poff << 4) | (unsigned)pw;
        // zero this row's pad slots (replaces the global memset)
        for (int s = c; s < 8 * pw; ++s) epack[poff + s] = 0;
    }
    __syncthreads();
    unsigned bend = (unsigned)((b + 1) * PBSTRIDE);
    for (int j = t; j < cnt; j += 512) {
        uint2 e = staging[sbase + j];
        int p = atomicAdd(&cur[e.y & (BWIDTH - 1)], 1);
        if ((unsigned)p < bend) epack[p] = e.x;
    }
}

// ---- u8 helpers ----
__device__ __forceinline__ float ubf0(unsigned x) { return (float)(x & 0xffu); }
__device__ __forceinline__ float ubf1(unsigned x) { return (float)((x >> 8) & 0xffu); }
__device__ __forceinline__ float ubf2(unsigned x) { return (float)((x >> 16) & 0xffu); }
__device__ __forceinline__ float ubf3(unsigned x) { return (float)(x >> 24); }

// ---- init: quantize original fp32 embeddings into u8 X + per-row scale ----
// 8-lane group per row; lane owns 8 dims.
__global__ void initq_kernel(const float* __restrict__ ue, const float* __restrict__ ie,
                             unsigned char* __restrict__ x8, float* __restrict__ scl) {
    int gid = blockIdx.x * blockDim.x + threadIdx.x;
    int row = gid >> 3;
    if (row >= N_NODES) return;
    int l8 = threadIdx.x & 7;
    const float* srcp = (row < N_USERS) ? (ue + (size_t)row * EMB)
                                        : (ie + (size_t)(row - N_USERS) * EMB);
    const float4* p = (const float4*)(srcp + l8 * 8);
    float4 f0 = p[0], f1 = p[1];
    float v[8] = {f0.x, f0.y, f0.z, f0.w, f1.x, f1.y, f1.z, f1.w};
    float m = 0.f;
    #pragma unroll
    for (int k = 0; k < 8; ++k) m = fmaxf(m, fabsf(v[k]));
    m = fmaxf(m, __shfl_xor(m, 1, 64));
    m = fmaxf(m, __shfl_xor(m, 2, 64));
    m = fmaxf(m, __shfl_xor(m, 4, 64));
    float inv = (m > 0.f) ? 127.f / m : 0.f;
    unsigned w0 = 0, w1 = 0;
    #pragma unroll
    for (int k = 0; k < 4; ++k)
        w0 |= (((unsigned)((int)rintf(v[k] * inv) + 128)) & 0xffu) << (8 * k);
    #pragma unroll
    for (int k = 0; k < 4; ++k)
        w1 |= (((unsigned)((int)rintf(v[4 + k] * inv) + 128)) & 0xffu) << (8 * k);
    *(uint2*)(x8 + (((size_t)row) << 6) + l8 * 8) = make_uint2(w0, w1);
    if (l8 == 0) scl[row] = m * (1.f / 127.f);
}

// ---- layer-0 acc term from ORIGINAL fp32 embeddings (exact) ----
__global__ void gather_init_kernel(const float* __restrict__ ue, const float* __restrict__ ie,
                                   const int* __restrict__ users, const int* __restrict__ items,
                                   float* __restrict__ accb) {
    int gid = blockIdx.x * blockDim.x + threadIdx.x;
    int w = gid >> 6;
    int lane = threadIdx.x & 63;
    if (w >= BATCH * 2) return;
    int b = w >> 1;
    float v;
    if (w & 1) v = ie[(long long)items[b] * EMB + lane];
    else       v = ue[(long long)users[b] * EMB + lane];
    accb[(long long)w * EMB + lane] = v;
}

// ---- accb += dequant(x8[sel]) ----
__global__ void gather_addq_kernel(const unsigned char* __restrict__ x8,
                                   const float* __restrict__ scl,
                                   const int* __restrict__ users, const int* __restrict__ items,
                                   float* __restrict__ accb) {
    int gid = blockIdx.x * blockDim.x + threadIdx.x;
    int w = gid >> 6;
    int lane = threadIdx.x & 63;
    if (w >= BATCH * 2) return;
    int b = w >> 1;
    int node = (w & 1) ? (N_USERS + items[b]) : users[b];
    float s = scl[node];
    float xv = s * ((float)x8[(((size_t)node) << 6) + lane] - 128.f);
    accb[(long long)w * EMB + lane] += xv;
}

// ---- padded row gather, u8 source: 8-lane group per row, 8-edge windows.
//      Holder lane decodes (byte-offset, val*scale[dst]) once, broadcasts
//      via shfl. acc_d = sum(vs*byte_d) - 128*sum(vs). ----
__device__ __forceinline__ void row_gather_q8(unsigned pr, int lane,
                                              const unsigned* __restrict__ epack,
                                              const unsigned char* __restrict__ x8,
                                              const float* __restrict__ scl,
                                              float acc[8]) {
    const int l8 = lane & 7;
    const int qb = lane & 56;                        // group base lane in wave
    const unsigned li8 = (unsigned)l8 * 8u;          // byte offset within 64B row
    float a0 = 0, a1 = 0, a2 = 0, a3 = 0, a4 = 0, a5 = 0, a6 = 0, a7 = 0;
    float b0 = 0, b1 = 0, b2 = 0, b3 = 0, b4 = 0, b5 = 0, b6 = 0, b7 = 0;
    float S = 0.f;
    const unsigned* ep = epack + (pr >> 4);
    int nwin = (int)(pr & 15u);
    if (nwin > 0) {
        unsigned e = ep[l8];
        for (int w = 0; w < nwin; ++w) {
            unsigned en = ep[8 + l8];                // prefetch next window
            ep += 8;                                 // (over-read lands in prow, safe)
            unsigned d = e & 0x3FFFFu;
            float v = ((float)(e >> 18) + 0.5f) * QINV;
            float vs = v * scl[d];                   // scale gather: 600KB, L2-hot
            unsigned voff = d << 6;                  // 64B row byte offset
            #pragma unroll
            for (int t = 0; t < 8; t += 2) {
                unsigned offA = (unsigned)__shfl((int)voff, qb + t, 64);
                unsigned offB = (unsigned)__shfl((int)voff, qb + t + 1, 64);
                float vA = __shfl(vs, qb + t, 64);
                float vB = __shfl(vs, qb + t + 1, 64);
                uint2 pa = *(const uint2*)(x8 + (offA | li8));
                uint2 pb = *(const uint2*)(x8 + (offB | li8));
                a0 += vA * ubf0(pa.x);  a1 += vA * ubf1(pa.x);
                a2 += vA * ubf2(pa.x);  a3 += vA * ubf3(pa.x);
                a4 += vA * ubf0(pa.y);  a5 += vA * ubf1(pa.y);
                a6 += vA * ubf2(pa.y);  a7 += vA * ubf3(pa.y);
                b0 += vB * ubf0(pb.x);  b1 += vB * ubf1(pb.x);
                b2 += vB * ubf2(pb.x);  b3 += vB * ubf3(pb.x);
                b4 += vB * ubf0(pb.y);  b5 += vB * ubf1(pb.y);
                b6 += vB * ubf2(pb.y);  b7 += vB * ubf3(pb.y);
                S += vA + vB;
            }
            e = en;
        }
    }
    float c = 128.f * S;
    acc[0] = a0 + b0 - c; acc[1] = a1 + b1 - c; acc[2] = a2 + b2 - c;
    acc[3] = a3 + b3 - c; acc[4] = a4 + b4 - c; acc[5] = a5 + b5 - c;
    acc[6] = a6 + b6 - c; acc[7] = a7 + b7 - c;
}

// ---- full SpMM: one 8-lane group per output row, u8 in / u8+scale out ----
__global__ void spmmq_kernel(const unsigned* __restrict__ prow,
                             const unsigned* __restrict__ epack,
                             const unsigned char* __restrict__ x8,
                             const float* __restrict__ sclin,
                             unsigned char* __restrict__ y8,
                             float* __restrict__ sclout) {
    int gid = blockIdx.x * blockDim.x + threadIdx.x;
    int row = gid >> 3;
    if (row >= N_NODES) return;
    int lane = threadIdx.x & 63;
    float acc[8];
    row_gather_q8(prow[row], lane, epack, x8, sclin, acc);
    float m = 0.f;
    #pragma unroll
    for (int k = 0; k < 8; ++k) m = fmaxf(m, fabsf(acc[k]));
    m = fmaxf(m, __shfl_xor(m, 1, 64));
    m = fmaxf(m, __shfl_xor(m, 2, 64));
    m = fmaxf(m, __shfl_xor(m, 4, 64));
    float inv = (m > 0.f) ? 127.f / m : 0.f;
    unsigned w0 = 0, w1 = 0;
    #pragma unroll
    for (int k = 0; k < 4; ++k)
        w0 |= (((unsigned)((int)rintf(acc[k] * inv) + 128)) & 0xffu) << (8 * k);
    #pragma unroll
    for (int k = 0; k < 4; ++k)
        w1 |= (((unsigned)((int)rintf(acc[4 + k] * inv) + 128)) & 0xffu) << (8 * k);
    int l8 = lane & 7;
    *(uint2*)(y8 + (((size_t)row) << 6) + l8 * 8) = make_uint2(w0, w1);
    if (l8 == 0) sclout[row] = m * (1.f / 127.f);
}

// ---- layer-3 SpMM for selected rows only; adds fp32 straight into accb ----
__global__ void spmm_selq_kernel(const unsigned* __restrict__ prow,
                                 const unsigned* __restrict__ epack,
                                 const unsigned char* __restrict__ x8,
                                 const float* __restrict__ scl,
                                 const int* __restrict__ users, const int* __restrict__ items,
                                 float* __restrict__ accb) {
    int gid = blockIdx.x * blockDim.x + threadIdx.x;
    int g = gid >> 3;
    if (g >= BATCH * 2) return;
    int lane = threadIdx.x & 63;
    int b = g >> 1;
    int node = (g & 1) ? (N_USERS + items[b]) : users[b];
    float acc[8];
    row_gather_q8(prow[node], lane, epack, x8, scl, acc);
    float4* p = (float4*)(accb + ((long long)g << 6) + (lane & 7) * 8);
    float4 c0 = p[0], c1 = p[1];
    c0.x += acc[0]; c0.y += acc[1]; c0.z += acc[2]; c0.w += acc[3];
    c1.x += acc[4]; c1.y += acc[5]; c1.z += acc[6]; c1.w += acc[7];
    p[0] = c0; p[1] = c1;
}

// ---- scores ----
__global__ void score_kernel(const float* __restrict__ accb, float* __restrict__ out) {
    int gid = blockIdx.x * blockDim.x + threadIdx.x;
    int b = gid >> 6;
    int lane = threadIdx.x & 63;
    if (b >= BATCH) return;
    float a = accb[(long long)(2 * b) * EMB + lane];
    float c = accb[(long long)(2 * b + 1) * EMB + lane];
    float p = a * c;
    #pragma unroll
    for (int off = 32; off > 0; off >>= 1) p += __shfl_down(p, off, 64);
    if (lane == 0) out[b] = p * (1.0f / 16.0f);
}

extern "C" void kernel_launch(void* const* d_in, const int* in_sizes, int n_in,
                              void* d_out, int out_size, void* d_ws, size_t ws_size,
                              hipStream_t stream) {
    const float* user_emb  = (const float*)d_in[0];
    const float* item_emb  = (const float*)d_in[1];
    const float* graph_val = (const float*)d_in[2];
    const int*   graph_src = (const int*)d_in[3];
    const int*   graph_dst = (const int*)d_in[4];
    const int*   users     = (const int*)d_in[5];
    const int*   items     = (const int*)d_in[6];
    float* out = (float*)d_out;

    // workspace layout — ~87 MB total.
    // region0 (55.08 MB): staging during CSR build; afterwards A8|B8|accb|scales.
    char* base = (char*)d_ws;
    const size_t STAGE_BYTES = (size_t)BSTRIDE * NB * 8;        // 55,084,000
    const size_t XQBYTES = (size_t)N_NODES * 64;                // 9,600,000
    const size_t ACCB_BYTES = (size_t)BATCH * 2 * EMB * 4;      // 2,097,152
    const size_t PB_SLOTS = (size_t)PBSTRIDE * NB;              // 7,800,832
    uint2*         staging = (uint2*)base;
    unsigned char* A8      = (unsigned char*)base;
    unsigned char* B8      = A8 + XQBYTES;
    float*         accb    = (float*)(base + 2 * XQBYTES);
    float*         scA     = (float*)(base + 2 * XQBYTES + ACCB_BYTES);
    float*         scB     = scA + N_NODES;                     // ends ~22.5 MB
    unsigned*      epack   = (unsigned*)(base + STAGE_BYTES);   // 31.2 MB padded
    unsigned*      prow    = epack + PB_SLOTS;                  // 0.6 MB
    int*           gcur    = (int*)(prow + N_NODES);            // NB ints

    const int wblocks = (BATCH * 2 * 64) / 256;                 // 2048
    const int sblocks = (N_NODES * 8 + 255) / 256;              // 4688 (32 rows/block)
    const int selblocks = (BATCH * 2 * 8) / 256;                // 256

    // ---- CSR build: bucketed two-pass counting sort into padded layout ----
    gcur_init_kernel<<<(NB + 255) / 256, 256, 0, stream>>>(gcur);
    p1_bin_kernel<<<P1_BLOCKS, 256, 0, stream>>>(graph_src, graph_dst, graph_val,
                                                 gcur, staging);
    p2_sort_kernel<<<NB, 512, 0, stream>>>(gcur, staging, epack, prow);

    // ---- embeddings (staging now dead; A8/B8/accb/scales overlay it) ----
    initq_kernel<<<sblocks, 256, 0, stream>>>(user_emb, item_emb, A8, scA);
    gather_init_kernel<<<wblocks, 256, 0, stream>>>(user_emb, item_emb, users, items, accb);

    // layer 1: B = G.A ; accb += B[sel]
    spmmq_kernel<<<sblocks, 256, 0, stream>>>(prow, epack, A8, scA, B8, scB);
    gather_addq_kernel<<<wblocks, 256, 0, stream>>>(B8, scB, users, items, accb);

    // layer 2: A = G.B ; accb += A[sel]
    spmmq_kernel<<<sblocks, 256, 0, stream>>>(prow, epack, B8, scB, A8, scA);
    gather_addq_kernel<<<wblocks, 256, 0, stream>>>(A8, scA, users, items, accb);

    // layer 3: selected rows only, fp32 into accb
    spmm_selq_kernel<<<selblocks, 256, 0, stream>>>(prow, epack, A8, scA, users, items, accb);

    score_kernel<<<(BATCH * 64) / 256, 256, 0, stream>>>(accb, out);
}